// Round 11
// baseline (509.810 us; speedup 1.0000x reference)
//
#include <hip/hip_runtime.h>
#include <math.h>

#define T_SEQ 2048
#define C_DIM 1024
#define H_NUM 16
#define D_DIM 64

typedef _Float16 f16x8 __attribute__((ext_vector_type(8)));
typedef _Float16 f16x4 __attribute__((ext_vector_type(4)));
typedef float    f32x4_t __attribute__((ext_vector_type(4)));

// ---------------------------------------------------------------------------
// x (fp32) -> xh (fp16), element-count/4 float4 units
// ---------------------------------------------------------------------------
__global__ __launch_bounds__(256)
void ra_conv_f16(const float* __restrict__ src, _Float16* __restrict__ dst,
                 int n4) {
    int i = blockIdx.x * 256 + threadIdx.x;
    if (i >= n4) return;
    float4 v = reinterpret_cast<const float4*>(src)[i];
    f16x4 h = { (_Float16)v.x, (_Float16)v.y, (_Float16)v.z, (_Float16)v.w };
    reinterpret_cast<f16x4*>(dst)[i] = h;
}

// ---------------------------------------------------------------------------
// W[R][C] fp32 -> Wt[C][R] fp16 (transpose+convert), 64x64 LDS tiles.
// ---------------------------------------------------------------------------
__global__ __launch_bounds__(256)
void ra_transpose_conv(const float* __restrict__ W, _Float16* __restrict__ Wt,
                       int R, int C) {
    __shared__ _Float16 tile[64][68];   // +4 pad keeps f16x4 rows 8B-aligned
    const int tid = threadIdx.x;
    const int r0 = blockIdx.y * 64, c0 = blockIdx.x * 64;
#pragma unroll
    for (int i = 0; i < 4; ++i) {
        int s = tid + 256 * i;          // 64 rows x 16 float4 quads
        int r = s >> 4, cq = s & 15;
        float4 w = *reinterpret_cast<const float4*>(
            &W[(size_t)(r0 + r) * C + c0 + cq * 4]);
        f16x4 h = { (_Float16)w.x, (_Float16)w.y, (_Float16)w.z, (_Float16)w.w };
        *reinterpret_cast<f16x4*>(&tile[r][cq * 4]) = h;
    }
    __syncthreads();
#pragma unroll
    for (int i = 0; i < 4; ++i) {
        int s = tid + 256 * i;          // 64 cols x 16 row-quads
        int c = s >> 4, rq = s & 15;
        f16x4 o = { tile[rq * 4 + 0][c], tile[rq * 4 + 1][c],
                    tile[rq * 4 + 2][c], tile[rq * 4 + 3][c] };
        *reinterpret_cast<f16x4*>(&Wt[(size_t)(c0 + c) * R + r0 + rq * 4]) = o;
    }
}

// ---------------------------------------------------------------------------
// fp16 MFMA GEMM: C[M,N] = A[M,K] @ Bt[N,K]^T. BM=BN=128, BK=32, 4 waves.
// Staging now via global_load_lds width=16 (async direct-to-LDS): the old
// reg-staged loop wrote LDS byte s*16 for thread s == wave-uniform base
// (wave*64 + i*256)*16 + lane*16, exactly global_load_lds's dest rule, so
// the LDS image is byte-identical. vmcnt drained by __syncthreads.
// ---------------------------------------------------------------------------
template <bool F16OUT>
__global__ __launch_bounds__(256)
void ra_gemm_f16(const _Float16* __restrict__ A, const _Float16* __restrict__ Bt,
                 void* __restrict__ Cout, int M, int N, int K) {
    __shared__ _Float16 AhS[128 * 32];
    __shared__ _Float16 BhS[128 * 32];

    const int tid  = threadIdx.x;
    const int lane = tid & 63;
    const int wave = tid >> 6;
    const int wm   = wave >> 1, wn = wave & 1;
    const int lq   = lane & 15;      // fragment row/col
    const int lg   = lane >> 4;      // k-octet group
    const int row0 = blockIdx.y * 128;
    const int col0 = blockIdx.x * 128;

    f32x4_t acc[4][4];
#pragma unroll
    for (int i = 0; i < 4; ++i)
#pragma unroll
        for (int j = 0; j < 4; ++j) acc[i][j] = {0.f, 0.f, 0.f, 0.f};

    for (int k0 = 0; k0 < K; k0 += 32) {
        __syncthreads();
#pragma unroll
        for (int i = 0; i < 2; ++i) {
            int s = tid + 256 * i;
            int r = s >> 2, g = s & 3;
            const _Float16* ga = &A[(size_t)(row0 + r) * K + k0 + g * 8];
            const _Float16* gb = &Bt[(size_t)(col0 + r) * K + k0 + g * 8];
            int base = (wave * 64 + i * 256) * 16;   // wave-uniform LDS byte base
            __builtin_amdgcn_global_load_lds(
                (const __attribute__((address_space(1))) void*)ga,
                (__attribute__((address_space(3))) void*)((char*)AhS + base),
                16, 0, 0);
            __builtin_amdgcn_global_load_lds(
                (const __attribute__((address_space(1))) void*)gb,
                (__attribute__((address_space(3))) void*)((char*)BhS + base),
                16, 0, 0);
        }
        __syncthreads();

        f16x8 af[4], bf[4];
#pragma unroll
        for (int t = 0; t < 4; ++t) {
            af[t] = *reinterpret_cast<const f16x8*>(
                &AhS[(wm * 64 + t * 16 + lq) * 32 + lg * 8]);
            bf[t] = *reinterpret_cast<const f16x8*>(
                &BhS[(wn * 64 + t * 16 + lq) * 32 + lg * 8]);
        }
#pragma unroll
        for (int mt = 0; mt < 4; ++mt)
#pragma unroll
            for (int nt = 0; nt < 4; ++nt)
                acc[mt][nt] = __builtin_amdgcn_mfma_f32_16x16x32_f16(
                    af[mt], bf[nt], acc[mt][nt], 0, 0, 0);
    }

    // epilogue: D lane layout col=lane&15, row=4*(lane>>4)+r (m89-verified)
#pragma unroll
    for (int mt = 0; mt < 4; ++mt)
#pragma unroll
        for (int nt = 0; nt < 4; ++nt) {
            int c = col0 + wn * 64 + nt * 16 + lq;
#pragma unroll
            for (int r = 0; r < 4; ++r) {
                int rr = row0 + wm * 64 + mt * 16 + 4 * lg + r;
                if (F16OUT)
                    ((_Float16*)Cout)[(size_t)rr * N + c] =
                        (_Float16)acc[mt][nt][r];
                else
                    ((float*)Cout)[(size_t)rr * N + c] = acc[mt][nt][r];
            }
        }
}

// ---------------------------------------------------------------------------
// RoPE in-place on fp16 qkv (B,T,3C); folds the 1/8 softmax scale into q.
// ---------------------------------------------------------------------------
__global__ __launch_bounds__(256)
void ra_rope_f16(_Float16* __restrict__ qkv, int total) {
    int idx = blockIdx.x * 256 + threadIdx.x;
    if (idx >= total) return;
    int j   = idx & 31;
    int h   = (idx >> 5) & 15;
    int mtx = (idx >> 9) & 1;
    int bt  = idx >> 10;
    int t   = bt & (T_SEQ - 1);

    float inv = exp2f(-(float)j * 0.41524101186092029f);
    float ang = (float)t * inv;
    float s, c;
    sincosf(ang, &s, &c);
    float scale = (mtx == 0) ? 0.125f : 1.0f;   // q pre-scaled by 1/sqrt(D)

    size_t base = (size_t)bt * 3072 + (size_t)mtx * 1024 + h * 64 + j;
    float q0 = (float)qkv[base];
    float q1 = (float)qkv[base + 32];
    qkv[base]      = (_Float16)((q0 * c - q1 * s) * scale);
    qkv[base + 32] = (_Float16)((q1 * c + q0 * s) * scale);
}

// ---------------------------------------------------------------------------
// Flash attention, fp16 MFMA (16x16x32, fp32 accum).
// R10 profile: VALU-bound (VALUBusy 62%, MfmaUtil 17%) on staging+addressing.
// Change vs R10: K is NOT LDS-staged anymore -- K fragments (8 contiguous
// f16) load directly from global (K slab 512KB/head is L2-resident, shared
// by 32 q-blocks; guide lesson: staging L2-fit data is pure overhead).
// Barrier structure unchanged; V staging + P^T LDS (with write->read barrier,
// round-9 lesson) unchanged. LDS 24KB -> 16KB.
// ---------------------------------------------------------------------------
__global__ __launch_bounds__(256)
void ra_attn_mfma(const _Float16* __restrict__ qkv, _Float16* __restrict__ Y) {
    __shared__ __align__(16) unsigned char smem_raw[16384];
    _Float16* Vt = (_Float16*)smem_raw;            // [64 d][64 kv]   8KB
    _Float16* Pt = (_Float16*)(smem_raw + 8192);   // [4w][16 q][64]  8KB

    const int tid  = threadIdx.x;
    const int lane = tid & 63;
    const int wave = tid >> 6;
    const int lq   = lane & 15;
    const int lg   = lane >> 4;
    const int swz  = (lq & 7) << 3;

    const int t0 = blockIdx.x * 64;
    const int h  = blockIdx.y;
    const int b  = blockIdx.z;

    const _Float16* Qg = qkv + (size_t)b * T_SEQ * 3072 + h * 64;
    const _Float16* Kg = Qg + 1024;
    const _Float16* Vg = Qg + 2048;

    // Q fragments (B operand of St): q pre-scaled by RoPE, direct f16x8 loads
    f16x8 qf[2];
    {
        const _Float16* qrow = Qg + (size_t)(t0 + wave * 16 + lq) * 3072 + lg * 8;
        qf[0] = *reinterpret_cast<const f16x8*>(qrow);
        qf[1] = *reinterpret_cast<const f16x8*>(qrow + 32);
    }
    // per-lane K base: row lq, octet lg (row stride 3072)
    const _Float16* Kl = Kg + (size_t)lq * 3072 + lg * 8;

    const f32x4_t vzero = {0.f, 0.f, 0.f, 0.f};
    float m_run = -1e30f, l_run = 0.f;
    f32x4_t o[4];
#pragma unroll
    for (int i = 0; i < 4; ++i) o[i] = vzero;

    const int dsub = tid & 15, kvq = tid >> 4;

    for (int kt = 0; kt < T_SEQ / 64; ++kt) {
        __syncthreads();                       // guard Vt reuse (prev PV done)
        const int kvb = kt * 64;
        // stage V transposed [d][kv^((d&7)<<3)]: 2B gathers (V slab L2-hot)
#pragma unroll
        for (int i = 0; i < 4; ++i) {
            int d = dsub + 16 * i;
            const _Float16* vcol = &Vg[(size_t)(kvb + kvq * 4) * 3072 + d];
            f16x4 hh = { vcol[0], vcol[3072], vcol[6144], vcol[9216] };
            *reinterpret_cast<f16x4*>(
                &Vt[d * 64 + ((kvq * 4) ^ ((d & 7) << 3))]) = hh;
        }
        __syncthreads();

        // St[t] = K_tile(t) @ Q^T; K fragments direct from global (L2-hot)
        f32x4_t st[4];
#pragma unroll
        for (int t = 0; t < 4; ++t) {
            st[t] = vzero;
#pragma unroll
            for (int mk = 0; mk < 2; ++mk) {
                f16x8 ak = *reinterpret_cast<const f16x8*>(
                    Kl + (size_t)(kvb + t * 16) * 3072 + mk * 32);
                st[t] = __builtin_amdgcn_mfma_f32_16x16x32_f16(
                    ak, qf[mk], st[t], 0, 0, 0);
            }
        }

        // online softmax for q-row lq (16 keys/lane, reduce over lg groups)
        float mloc = -1e30f;
#pragma unroll
        for (int t = 0; t < 4; ++t)
#pragma unroll
            for (int r = 0; r < 4; ++r) mloc = fmaxf(mloc, st[t][r]);
        mloc = fmaxf(mloc, __shfl_xor(mloc, 16));
        mloc = fmaxf(mloc, __shfl_xor(mloc, 32));
        float mnew  = fmaxf(m_run, mloc);
        float alpha = __expf(m_run - mnew);
        float rs = 0.f;
        float p[4][4];
#pragma unroll
        for (int t = 0; t < 4; ++t)
#pragma unroll
            for (int r = 0; r < 4; ++r) {
                p[t][r] = __expf(st[t][r] - mnew);
                rs += p[t][r];
            }
        rs += __shfl_xor(rs, 16);
        rs += __shfl_xor(rs, 32);
        l_run = l_run * alpha + rs;
        m_run = mnew;
#pragma unroll
        for (int i = 0; i < 4; ++i) o[i] *= alpha;

        // P^T -> per-wave LDS [q=lq][kv ^ swz]
        _Float16* Pw = Pt + wave * 1024 + lq * 64;
#pragma unroll
        for (int t = 0; t < 4; ++t) {
            f16x4 ph = { (_Float16)p[t][0], (_Float16)p[t][1],
                         (_Float16)p[t][2], (_Float16)p[t][3] };
            *reinterpret_cast<f16x4*>(&Pw[(t * 16 + lg * 4) ^ swz]) = ph;
        }
        __syncthreads();   // P write->read sync (round-9-proven necessary)

        // Ot += V^T @ P^T
        f16x8 bp[2];
#pragma unroll
        for (int mk = 0; mk < 2; ++mk)
            bp[mk] = *reinterpret_cast<const f16x8*>(
                &Pw[(lg * 8 + mk * 32) ^ swz]);
#pragma unroll
        for (int dt = 0; dt < 4; ++dt) {
#pragma unroll
            for (int mk = 0; mk < 2; ++mk) {
                f16x8 av = *reinterpret_cast<const f16x8*>(
                    &Vt[(dt * 16 + lq) * 64 + ((lg * 8 + mk * 32) ^ swz)]);
                o[dt] = __builtin_amdgcn_mfma_f32_16x16x32_f16(
                    av, bp[mk], o[dt], 0, 0, 0);
            }
        }
    }

    // epilogue: Ot -> LDS f32 (quad-swizzle) -> Y fp16
    __syncthreads();
    float* Of = (float*)smem_raw;            // [64 q][64 d] 16KB (reuse all)
    {
        float inv = 1.0f / l_run;
        int q = wave * 16 + lq;
#pragma unroll
        for (int dt = 0; dt < 4; ++dt)
#pragma unroll
            for (int r = 0; r < 4; ++r) {
                int d = dt * 16 + lg * 4 + r;
                Of[q * 64 + (d ^ ((q & 7) << 2))] = o[dt][r] * inv;
            }
    }
    __syncthreads();
#pragma unroll
    for (int i = 0; i < 4; ++i) {
        int s = tid + 256 * i;
        int row = s >> 4, dq = s & 15;
        float4 v = *reinterpret_cast<float4*>(
            &Of[row * 64 + ((dq * 4) ^ ((row & 7) << 2))]);
        f16x4 hv = { (_Float16)v.x, (_Float16)v.y, (_Float16)v.z, (_Float16)v.w };
        *reinterpret_cast<f16x4*>(
            &Y[((size_t)b * T_SEQ + t0 + row) * C_DIM + h * 64 + dq * 4]) = hv;
    }
}

// ---------------------------------------------------------------------------
extern "C" void kernel_launch(void* const* d_in, const int* in_sizes, int n_in,
                              void* d_out, int out_size, void* d_ws, size_t ws_size,
                              hipStream_t stream) {
    const float* x      = (const float*)d_in[0];
    const float* W_attn = (const float*)d_in[1];
    const float* W_proj = (const float*)d_in[2];
    float* out = (float*)d_out;

    const int B = in_sizes[0] / (T_SEQ * C_DIM);   // 4
    const int M = B * T_SEQ;                        // 8192

    // fp16 workspace layout (byte offsets), total 88 MB < 128 MB
    unsigned char* ws = (unsigned char*)d_ws;
    _Float16* xh   = (_Float16*)(ws);                        // 16 MB
    _Float16* qkvh = (_Float16*)(ws + (16u << 20));          // 48 MB
    _Float16* Yh   = (_Float16*)(ws + (64u << 20));          // 16 MB
    _Float16* WaT  = (_Float16*)(ws + (80u << 20));          //  6 MB
    _Float16* WpT  = (_Float16*)(ws + (86u << 20));          //  2 MB

    // 1) convert x -> fp16
    int n4 = M * C_DIM / 4;
    hipLaunchKernelGGL(ra_conv_f16, dim3((n4 + 255) / 256), dim3(256), 0,
                       stream, x, xh, n4);

    // 2) transpose+convert weights to N-major fp16
    hipLaunchKernelGGL(ra_transpose_conv, dim3(3 * C_DIM / 64, C_DIM / 64),
                       dim3(256), 0, stream, W_attn, WaT, C_DIM, 3 * C_DIM);
    hipLaunchKernelGGL(ra_transpose_conv, dim3(C_DIM / 64, C_DIM / 64),
                       dim3(256), 0, stream, W_proj, WpT, C_DIM, C_DIM);

    // 3) qkv = x @ W_attn   (fp16 out)
    hipLaunchKernelGGL((ra_gemm_f16<true>), dim3(3 * C_DIM / 128, M / 128),
                       dim3(256), 0, stream, xh, WaT, (void*)qkvh,
                       M, 3 * C_DIM, C_DIM);

    // 4) RoPE in place on q,k (q pre-scaled by 1/8)
    int total = M * 2 * H_NUM * 32;
    hipLaunchKernelGGL(ra_rope_f16, dim3(total / 256), dim3(256), 0, stream,
                       qkvh, total);

    // 5) flash attention (fp16 MFMA) -> Yh
    hipLaunchKernelGGL(ra_attn_mfma, dim3(T_SEQ / 64, H_NUM, B), dim3(256), 0,
                       stream, qkvh, Yh);

    // 6) out = Y @ W_proj   (fp32 out)
    hipLaunchKernelGGL((ra_gemm_f16<false>), dim3(C_DIM / 128, M / 128),
                       dim3(256), 0, stream, Yh, WpT, (void*)out,
                       M, C_DIM, C_DIM);
}

// Round 12
// 366.248 us; speedup vs baseline: 1.3920x; 1.3920x over previous
//
#include <hip/hip_runtime.h>
#include <math.h>

#define T_SEQ 2048
#define C_DIM 1024
#define H_NUM 16
#define D_DIM 64

typedef _Float16 f16x8 __attribute__((ext_vector_type(8)));
typedef _Float16 f16x4 __attribute__((ext_vector_type(4)));
typedef float    f32x4_t __attribute__((ext_vector_type(4)));

// ---------------------------------------------------------------------------
// x (fp32) -> xh (fp16)
// ---------------------------------------------------------------------------
__global__ __launch_bounds__(256)
void ra_conv_f16(const float* __restrict__ src, _Float16* __restrict__ dst,
                 int n4) {
    int i = blockIdx.x * 256 + threadIdx.x;
    if (i >= n4) return;
    float4 v = reinterpret_cast<const float4*>(src)[i];
    f16x4 h = { (_Float16)v.x, (_Float16)v.y, (_Float16)v.z, (_Float16)v.w };
    reinterpret_cast<f16x4*>(dst)[i] = h;
}

// ---------------------------------------------------------------------------
// W[R][C] fp32 -> Wt[C][R] fp16 (transpose+convert), 64x64 LDS tiles.
// ---------------------------------------------------------------------------
__global__ __launch_bounds__(256)
void ra_transpose_conv(const float* __restrict__ W, _Float16* __restrict__ Wt,
                       int R, int C) {
    __shared__ _Float16 tile[64][68];   // +4 pad keeps f16x4 rows 8B-aligned
    const int tid = threadIdx.x;
    const int r0 = blockIdx.y * 64, c0 = blockIdx.x * 64;
#pragma unroll
    for (int i = 0; i < 4; ++i) {
        int s = tid + 256 * i;
        int r = s >> 4, cq = s & 15;
        float4 w = *reinterpret_cast<const float4*>(
            &W[(size_t)(r0 + r) * C + c0 + cq * 4]);
        f16x4 h = { (_Float16)w.x, (_Float16)w.y, (_Float16)w.z, (_Float16)w.w };
        *reinterpret_cast<f16x4*>(&tile[r][cq * 4]) = h;
    }
    __syncthreads();
#pragma unroll
    for (int i = 0; i < 4; ++i) {
        int s = tid + 256 * i;
        int c = s >> 4, rq = s & 15;
        f16x4 o = { tile[rq * 4 + 0][c], tile[rq * 4 + 1][c],
                    tile[rq * 4 + 2][c], tile[rq * 4 + 3][c] };
        *reinterpret_cast<f16x4*>(&Wt[(size_t)(c0 + c) * R + r0 + rq * 4]) = o;
    }
}

// ---------------------------------------------------------------------------
// One-shot V transpose: qkv V-slab (rows bt, stride 3072) ->
// VtG[b][h][d=64][t=2048] fp16. Block: one (b,h,64-t tile).
// Read coalesced rows -> LDS tile[64][70] (stride 140B: transposed scalar
// reads land 4-way max) -> coalesced 16B writes of VtG rows.
// ---------------------------------------------------------------------------
__global__ __launch_bounds__(256)
void ra_transpose_v(const _Float16* __restrict__ qkv,
                    _Float16* __restrict__ VtG) {
    __shared__ _Float16 tile[64][70];
    const int tid = threadIdx.x;
    const int tt = blockIdx.x, h = blockIdx.y, b = blockIdx.z;
    const _Float16* Vg = qkv + (size_t)b * T_SEQ * 3072 + 2048 + h * 64;
#pragma unroll
    for (int i = 0; i < 2; ++i) {
        int u = tid + 256 * i;          // t = u>>3, d-octet = u&7
        int t = u >> 3, doct = u & 7;
        f16x8 v = *reinterpret_cast<const f16x8*>(
            &Vg[(size_t)(tt * 64 + t) * 3072 + doct * 8]);
        *reinterpret_cast<f16x8*>(&tile[t][doct * 8]) = v;
    }
    __syncthreads();
#pragma unroll
    for (int i = 0; i < 2; ++i) {
        int u = tid + 256 * i;          // d = u>>3, t-octet = u&7
        int d = u >> 3, toct = u & 7;
        f16x8 o;
#pragma unroll
        for (int j = 0; j < 8; ++j) o[j] = tile[toct * 8 + j][d];
        *reinterpret_cast<f16x8*>(
            &VtG[((size_t)(b * H_NUM + h) * 64 + d) * T_SEQ
                 + tt * 64 + toct * 8]) = o;
    }
}

// ---------------------------------------------------------------------------
// fp16 MFMA GEMM (unchanged from R11 -- global_load_lds staging measured
// ~24us faster than reg-staging across GEMM1+GEMM2).
// ---------------------------------------------------------------------------
template <bool F16OUT>
__global__ __launch_bounds__(256)
void ra_gemm_f16(const _Float16* __restrict__ A, const _Float16* __restrict__ Bt,
                 void* __restrict__ Cout, int M, int N, int K) {
    __shared__ _Float16 AhS[128 * 32];
    __shared__ _Float16 BhS[128 * 32];

    const int tid  = threadIdx.x;
    const int lane = tid & 63;
    const int wave = tid >> 6;
    const int wm   = wave >> 1, wn = wave & 1;
    const int lq   = lane & 15;
    const int lg   = lane >> 4;
    const int row0 = blockIdx.y * 128;
    const int col0 = blockIdx.x * 128;

    f32x4_t acc[4][4];
#pragma unroll
    for (int i = 0; i < 4; ++i)
#pragma unroll
        for (int j = 0; j < 4; ++j) acc[i][j] = {0.f, 0.f, 0.f, 0.f};

    for (int k0 = 0; k0 < K; k0 += 32) {
        __syncthreads();
#pragma unroll
        for (int i = 0; i < 2; ++i) {
            int s = tid + 256 * i;
            int r = s >> 2, g = s & 3;
            const _Float16* ga = &A[(size_t)(row0 + r) * K + k0 + g * 8];
            const _Float16* gb = &Bt[(size_t)(col0 + r) * K + k0 + g * 8];
            int base = (wave * 64 + i * 256) * 16;   // wave-uniform LDS base
            __builtin_amdgcn_global_load_lds(
                (const __attribute__((address_space(1))) void*)ga,
                (__attribute__((address_space(3))) void*)((char*)AhS + base),
                16, 0, 0);
            __builtin_amdgcn_global_load_lds(
                (const __attribute__((address_space(1))) void*)gb,
                (__attribute__((address_space(3))) void*)((char*)BhS + base),
                16, 0, 0);
        }
        __syncthreads();

        f16x8 af[4], bf[4];
#pragma unroll
        for (int t = 0; t < 4; ++t) {
            af[t] = *reinterpret_cast<const f16x8*>(
                &AhS[(wm * 64 + t * 16 + lq) * 32 + lg * 8]);
            bf[t] = *reinterpret_cast<const f16x8*>(
                &BhS[(wn * 64 + t * 16 + lq) * 32 + lg * 8]);
        }
#pragma unroll
        for (int mt = 0; mt < 4; ++mt)
#pragma unroll
            for (int nt = 0; nt < 4; ++nt)
                acc[mt][nt] = __builtin_amdgcn_mfma_f32_16x16x32_f16(
                    af[mt], bf[nt], acc[mt][nt], 0, 0, 0);
    }

#pragma unroll
    for (int mt = 0; mt < 4; ++mt)
#pragma unroll
        for (int nt = 0; nt < 4; ++nt) {
            int c = col0 + wn * 64 + nt * 16 + lq;
#pragma unroll
            for (int r = 0; r < 4; ++r) {
                int rr = row0 + wm * 64 + mt * 16 + 4 * lg + r;
                if (F16OUT)
                    ((_Float16*)Cout)[(size_t)rr * N + c] =
                        (_Float16)acc[mt][nt][r];
                else
                    ((float*)Cout)[(size_t)rr * N + c] = acc[mt][nt][r];
            }
        }
}

// ---------------------------------------------------------------------------
// RoPE in-place on fp16 qkv (q,k only; V untouched -> safe to pre-transpose V)
// ---------------------------------------------------------------------------
__global__ __launch_bounds__(256)
void ra_rope_f16(_Float16* __restrict__ qkv, int total) {
    int idx = blockIdx.x * 256 + threadIdx.x;
    if (idx >= total) return;
    int j   = idx & 31;
    int h   = (idx >> 5) & 15;
    int mtx = (idx >> 9) & 1;
    int bt  = idx >> 10;
    int t   = bt & (T_SEQ - 1);

    float inv = exp2f(-(float)j * 0.41524101186092029f);
    float ang = (float)t * inv;
    float s, c;
    sincosf(ang, &s, &c);
    float scale = (mtx == 0) ? 0.125f : 1.0f;

    size_t base = (size_t)bt * 3072 + (size_t)mtx * 1024 + h * 64 + j;
    float q0 = (float)qkv[base];
    float q1 = (float)qkv[base + 32];
    qkv[base]      = (_Float16)((q0 * c - q1 * s) * scale);
    qkv[base + 32] = (_Float16)((q1 * c + q0 * s) * scale);
}

// ---------------------------------------------------------------------------
// Flash attention (R10-proven structure: K LDS-staged -- R11's direct-global
// K was latency-bound, scattered 16B @ 6KB stride; reverted).
// V now staged from pre-transposed VtG: 2 coalesced 16B loads + 2 b128 LDS
// writes per thread, replacing R10's 16 scalar 2B gathers (the VALU/VMEM
// hotspot). Vt LDS image is byte-identical to R10 (octet-XOR == quad-XOR
// here since the XOR mask only touches bits >=3). All barriers as R10,
// incl. the round-9-proven P write->read barrier.
// ---------------------------------------------------------------------------
__global__ __launch_bounds__(256)
void ra_attn_mfma(const _Float16* __restrict__ qkv,
                  const _Float16* __restrict__ VtG,
                  _Float16* __restrict__ Y) {
    __shared__ __align__(16) unsigned char smem_raw[24576];
    _Float16* Ks = (_Float16*)smem_raw;            // [64 kv][64 d]   8KB
    _Float16* Vt = (_Float16*)(smem_raw + 8192);   // [64 d][64 kv]   8KB
    _Float16* Pt = (_Float16*)(smem_raw + 16384);  // [4w][16 q][64]  8KB

    const int tid  = threadIdx.x;
    const int lane = tid & 63;
    const int wave = tid >> 6;
    const int lq   = lane & 15;
    const int lg   = lane >> 4;
    const int swz  = (lq & 7) << 3;

    const int t0 = blockIdx.x * 64;
    const int h  = blockIdx.y;
    const int b  = blockIdx.z;

    const _Float16* Qg = qkv + (size_t)b * T_SEQ * 3072 + h * 64;
    const _Float16* Kg = Qg + 1024;
    const _Float16* Vt_g = VtG + (size_t)(b * H_NUM + h) * 64 * T_SEQ;

    f16x8 qf[2];
    {
        const _Float16* qrow = Qg + (size_t)(t0 + wave * 16 + lq) * 3072 + lg * 8;
        qf[0] = *reinterpret_cast<const f16x8*>(qrow);
        qf[1] = *reinterpret_cast<const f16x8*>(qrow + 32);
    }

    const f32x4_t vzero = {0.f, 0.f, 0.f, 0.f};
    float m_run = -1e30f, l_run = 0.f;
    f32x4_t o[4];
#pragma unroll
    for (int i = 0; i < 4; ++i) o[i] = vzero;

    for (int kt = 0; kt < T_SEQ / 64; ++kt) {
        __syncthreads();                       // guard Ks/Vt reuse
        const int kvb = kt * 64;
        // stage K [kv][d^((kv&7)<<3)]: f16x4 copies, coalesced (R10-proven)
#pragma unroll
        for (int i = 0; i < 4; ++i) {
            int s  = tid + 256 * i;
            int kv = s >> 4, dq = s & 15;
            f16x4 hh = *reinterpret_cast<const f16x4*>(
                &Kg[(size_t)(kvb + kv) * 3072 + dq * 4]);
            *reinterpret_cast<f16x4*>(
                &Ks[kv * 64 + ((dq * 4) ^ ((kv & 7) << 3))]) = hh;
        }
        // stage V from VtG: coalesced 16B row loads, b128 swizzled LDS writes
#pragma unroll
        for (int i = 0; i < 2; ++i) {
            int u = tid + 256 * i;             // d = u>>3, kv-octet = u&7
            int d = u >> 3, koct = u & 7;
            f16x8 vv = *reinterpret_cast<const f16x8*>(
                &Vt_g[(size_t)d * T_SEQ + kvb + koct * 8]);
            *reinterpret_cast<f16x8*>(
                &Vt[d * 64 + ((koct * 8) ^ ((d & 7) << 3))]) = vv;
        }
        __syncthreads();

        // St[t] = K_tile(t) @ Q^T
        f32x4_t st[4];
#pragma unroll
        for (int t = 0; t < 4; ++t) {
            st[t] = vzero;
#pragma unroll
            for (int mk = 0; mk < 2; ++mk) {
                f16x8 ak = *reinterpret_cast<const f16x8*>(
                    &Ks[(t * 16 + lq) * 64 + ((lg * 8 + mk * 32) ^ swz)]);
                st[t] = __builtin_amdgcn_mfma_f32_16x16x32_f16(
                    ak, qf[mk], st[t], 0, 0, 0);
            }
        }

        // online softmax for q-row lq
        float mloc = -1e30f;
#pragma unroll
        for (int t = 0; t < 4; ++t)
#pragma unroll
            for (int r = 0; r < 4; ++r) mloc = fmaxf(mloc, st[t][r]);
        mloc = fmaxf(mloc, __shfl_xor(mloc, 16));
        mloc = fmaxf(mloc, __shfl_xor(mloc, 32));
        float mnew  = fmaxf(m_run, mloc);
        float alpha = __expf(m_run - mnew);
        float rs = 0.f;
        float p[4][4];
#pragma unroll
        for (int t = 0; t < 4; ++t)
#pragma unroll
            for (int r = 0; r < 4; ++r) {
                p[t][r] = __expf(st[t][r] - mnew);
                rs += p[t][r];
            }
        rs += __shfl_xor(rs, 16);
        rs += __shfl_xor(rs, 32);
        l_run = l_run * alpha + rs;
        m_run = mnew;
#pragma unroll
        for (int i = 0; i < 4; ++i) o[i] *= alpha;

        // P^T -> per-wave LDS [q=lq][kv ^ swz]
        _Float16* Pw = Pt + wave * 1024 + lq * 64;
#pragma unroll
        for (int t = 0; t < 4; ++t) {
            f16x4 ph = { (_Float16)p[t][0], (_Float16)p[t][1],
                         (_Float16)p[t][2], (_Float16)p[t][3] };
            *reinterpret_cast<f16x4*>(&Pw[(t * 16 + lg * 4) ^ swz]) = ph;
        }
        __syncthreads();   // P write->read sync (round-9-proven necessary)

        // Ot += V^T @ P^T
        f16x8 bp[2];
#pragma unroll
        for (int mk = 0; mk < 2; ++mk)
            bp[mk] = *reinterpret_cast<const f16x8*>(
                &Pw[(lg * 8 + mk * 32) ^ swz]);
#pragma unroll
        for (int dt = 0; dt < 4; ++dt) {
#pragma unroll
            for (int mk = 0; mk < 2; ++mk) {
                f16x8 av = *reinterpret_cast<const f16x8*>(
                    &Vt[(dt * 16 + lq) * 64 + ((lg * 8 + mk * 32) ^ swz)]);
                o[dt] = __builtin_amdgcn_mfma_f32_16x16x32_f16(
                    av, bp[mk], o[dt], 0, 0, 0);
            }
        }
    }

    // epilogue: Ot -> LDS f32 (quad-swizzle) -> Y fp16
    __syncthreads();
    float* Of = (float*)smem_raw;            // [64 q][64 d] 16KB (reuse)
    {
        float inv = 1.0f / l_run;
        int q = wave * 16 + lq;
#pragma unroll
        for (int dt = 0; dt < 4; ++dt)
#pragma unroll
            for (int r = 0; r < 4; ++r) {
                int d = dt * 16 + lg * 4 + r;
                Of[q * 64 + (d ^ ((q & 7) << 2))] = o[dt][r] * inv;
            }
    }
    __syncthreads();
#pragma unroll
    for (int i = 0; i < 4; ++i) {
        int s = tid + 256 * i;
        int row = s >> 4, dq = s & 15;
        float4 v = *reinterpret_cast<float4*>(
            &Of[row * 64 + ((dq * 4) ^ ((row & 7) << 2))]);
        f16x4 hv = { (_Float16)v.x, (_Float16)v.y, (_Float16)v.z, (_Float16)v.w };
        *reinterpret_cast<f16x4*>(
            &Y[((size_t)b * T_SEQ + t0 + row) * C_DIM + h * 64 + dq * 4]) = hv;
    }
}

// ---------------------------------------------------------------------------
extern "C" void kernel_launch(void* const* d_in, const int* in_sizes, int n_in,
                              void* d_out, int out_size, void* d_ws, size_t ws_size,
                              hipStream_t stream) {
    const float* x      = (const float*)d_in[0];
    const float* W_attn = (const float*)d_in[1];
    const float* W_proj = (const float*)d_in[2];
    float* out = (float*)d_out;

    const int B = in_sizes[0] / (T_SEQ * C_DIM);   // 4
    const int M = B * T_SEQ;                        // 8192

    // workspace layout (byte offsets), total 104 MB < 128 MB
    unsigned char* ws = (unsigned char*)d_ws;
    _Float16* xh   = (_Float16*)(ws);                        // 16 MB
    _Float16* qkvh = (_Float16*)(ws + (16u << 20));          // 48 MB
    _Float16* Yh   = (_Float16*)(ws + (64u << 20));          // 16 MB
    _Float16* WaT  = (_Float16*)(ws + (80u << 20));          //  6 MB
    _Float16* WpT  = (_Float16*)(ws + (86u << 20));          //  2 MB
    _Float16* VtG  = (_Float16*)(ws + (88u << 20));          // 16 MB

    // 1) convert x -> fp16
    int n4 = M * C_DIM / 4;
    hipLaunchKernelGGL(ra_conv_f16, dim3((n4 + 255) / 256), dim3(256), 0,
                       stream, x, xh, n4);

    // 2) transpose+convert weights to N-major fp16
    hipLaunchKernelGGL(ra_transpose_conv, dim3(3 * C_DIM / 64, C_DIM / 64),
                       dim3(256), 0, stream, W_attn, WaT, C_DIM, 3 * C_DIM);
    hipLaunchKernelGGL(ra_transpose_conv, dim3(C_DIM / 64, C_DIM / 64),
                       dim3(256), 0, stream, W_proj, WpT, C_DIM, C_DIM);

    // 3) qkv = x @ W_attn   (fp16 out)
    hipLaunchKernelGGL((ra_gemm_f16<true>), dim3(3 * C_DIM / 128, M / 128),
                       dim3(256), 0, stream, xh, WaT, (void*)qkvh,
                       M, 3 * C_DIM, C_DIM);

    // 4) RoPE in place on q,k (q pre-scaled by 1/8)
    int total = M * 2 * H_NUM * 32;
    hipLaunchKernelGGL(ra_rope_f16, dim3(total / 256), dim3(256), 0, stream,
                       qkvh, total);

    // 5) pre-transpose V -> VtG[b,h,d,t]
    hipLaunchKernelGGL(ra_transpose_v, dim3(T_SEQ / 64, H_NUM, B), dim3(256),
                       0, stream, qkvh, VtG);

    // 6) flash attention (fp16 MFMA) -> Yh
    hipLaunchKernelGGL(ra_attn_mfma, dim3(T_SEQ / 64, H_NUM, B), dim3(256), 0,
                       stream, qkvh, VtG, Yh);

    // 7) out = Y @ W_proj   (fp32 out)
    hipLaunchKernelGGL((ra_gemm_f16<false>), dim3(C_DIM / 128, M / 128),
                       dim3(256), 0, stream, Yh, WpT, (void*)out,
                       M, C_DIM, C_DIM);
}